// Round 8
// baseline (304.557 us; speedup 1.0000x reference)
//
#include <hip/hip_runtime.h>
#include <hip/hip_fp16.h>

#define N_NODES 100000
#define N_EDGES 1600000
#define NPART 8
#define PSZ 12500

// ---------------- workspace layout (bytes) ----------------
#define WS_OFF   0                 // int[N+1]
#define WS_DEG   400016            // int[N]
#define WS_CUR   800016            // int[N]
#define WS_BSUM  1200016           // int[512]
#define WS_PCUR  1202064           // int[8]
#define WS_SJ    1202096           // int[E]        (6.4 MB)
#define WS_WCOMB 7602096           // float[64*64]
#define WS_BCOMB 7618480           // float[64]
#define WS_Q     7618736           // __half[N*64]  (12.8 MB)
#define WS_BIN   20418736          // int2[E]       (12.8 MB)  total ~33.2 MB

#define XP 68   // padded LDS row pitch (floats)

__global__ void k_zero(int* deg) {
    int t = blockIdx.x * blockDim.x + threadIdx.x;
    if (t < N_NODES) deg[t] = 0;
}

// single-pass degree count, int4 loads
__global__ void __launch_bounds__(256) k_count(const int* __restrict__ ei, int* deg) {
    int e = (blockIdx.x * 256 + threadIdx.x) * 4;
    if (e < N_EDGES) {
        int4 iv = *(const int4*)(ei + e);
        atomicAdd(&deg[iv.x], 1);
        atomicAdd(&deg[iv.y], 1);
        atomicAdd(&deg[iv.z], 1);
        atomicAdd(&deg[iv.w], 1);
    }
}

__global__ void k_scan1(const int* __restrict__ deg, int* off, int* bsum) {
    __shared__ int s[256];
    int t = blockIdx.x * 256 + threadIdx.x;
    int v = (t < N_NODES) ? deg[t] : 0;
    s[threadIdx.x] = v;
    __syncthreads();
    for (int o = 1; o < 256; o <<= 1) {
        int add = (threadIdx.x >= o) ? s[threadIdx.x - o] : 0;
        __syncthreads();
        s[threadIdx.x] += add;
        __syncthreads();
    }
    if (t < N_NODES) off[t] = s[threadIdx.x] - v;
    if (threadIdx.x == 255) bsum[blockIdx.x] = s[255];
}

__global__ void k_scan2(int* bsum, int nb) {
    __shared__ int s[512];
    int v = (threadIdx.x < nb) ? bsum[threadIdx.x] : 0;
    s[threadIdx.x] = v;
    __syncthreads();
    for (int o = 1; o < 512; o <<= 1) {
        int add = (threadIdx.x >= o) ? s[threadIdx.x - o] : 0;
        __syncthreads();
        s[threadIdx.x] += add;
        __syncthreads();
    }
    if (threadIdx.x < nb) bsum[threadIdx.x] = s[threadIdx.x] - v;
}

// final offsets + cur init + per-partition bin cursors
__global__ void k_scan3(const int* __restrict__ deg, int* off,
                        const int* __restrict__ bsum, int* cur, int* pcur) {
    int t = blockIdx.x * 256 + threadIdx.x;
    if (t < N_NODES) {
        int o = off[t] + bsum[blockIdx.x];
        off[t] = o;
        cur[t] = o;
        if (t == N_NODES - 1) off[N_NODES] = o + deg[t];
        if ((t % PSZ) == 0) pcur[t / PSZ] = o;
    }
}

// bin edges into partition-contiguous (i,j) buckets; block-aggregated cursors
__global__ void __launch_bounds__(256) k_bin(const int* __restrict__ ei,
                                             const int* __restrict__ ej,
                                             int* pcur, int2* __restrict__ binned) {
    __shared__ int cnt[NPART];
    __shared__ int base[NPART];
    int t = threadIdx.x;
    if (t < NPART) cnt[t] = 0;
    __syncthreads();

    int e0 = blockIdx.x * 2048 + t * 4;
    int e1 = e0 + 1024;
    bool v0 = e0 < N_EDGES, v1 = e1 < N_EDGES;
    int4 i0, j0, i1, j1;
    int p0[4], s0[4], p1[4], s1[4];
    if (v0) {
        i0 = *(const int4*)(ei + e0); j0 = *(const int4*)(ej + e0);
        p0[0] = i0.x / PSZ; s0[0] = atomicAdd(&cnt[p0[0]], 1);
        p0[1] = i0.y / PSZ; s0[1] = atomicAdd(&cnt[p0[1]], 1);
        p0[2] = i0.z / PSZ; s0[2] = atomicAdd(&cnt[p0[2]], 1);
        p0[3] = i0.w / PSZ; s0[3] = atomicAdd(&cnt[p0[3]], 1);
    }
    if (v1) {
        i1 = *(const int4*)(ei + e1); j1 = *(const int4*)(ej + e1);
        p1[0] = i1.x / PSZ; s1[0] = atomicAdd(&cnt[p1[0]], 1);
        p1[1] = i1.y / PSZ; s1[1] = atomicAdd(&cnt[p1[1]], 1);
        p1[2] = i1.z / PSZ; s1[2] = atomicAdd(&cnt[p1[2]], 1);
        p1[3] = i1.w / PSZ; s1[3] = atomicAdd(&cnt[p1[3]], 1);
    }
    __syncthreads();
    if (t < NPART) base[t] = cnt[t] ? atomicAdd(&pcur[t], cnt[t]) : 0;
    __syncthreads();
    if (v0) {
        binned[base[p0[0]] + s0[0]] = make_int2(i0.x, j0.x);
        binned[base[p0[1]] + s0[1]] = make_int2(i0.y, j0.y);
        binned[base[p0[2]] + s0[2]] = make_int2(i0.z, j0.z);
        binned[base[p0[3]] + s0[3]] = make_int2(i0.w, j0.w);
    }
    if (v1) {
        binned[base[p1[0]] + s1[0]] = make_int2(i1.x, j1.x);
        binned[base[p1[1]] + s1[1]] = make_int2(i1.y, j1.y);
        binned[base[p1[2]] + s1[2]] = make_int2(i1.z, j1.z);
        binned[base[p1[3]] + s1[3]] = make_int2(i1.w, j1.w);
    }
}

// per-partition CSR fill from the partition's bucket (L2-resident slice)
__global__ void __launch_bounds__(256) k_fill2(const int2* __restrict__ binned,
                                               const int* __restrict__ off,
                                               int* cur, int* __restrict__ sj) {
    int p = blockIdx.x & (NPART - 1);
    int w = blockIdx.x >> 3;                 // 0..31
    int start = off[p * PSZ];
    int end   = off[(p + 1) * PSZ];          // p=7 -> off[N_NODES]
    for (int e = start + w * 256 + threadIdx.x; e < end; e += 32 * 256) {
        int2 ij = binned[e];
        sj[atomicAdd(&cur[ij.x], 1)] = ij.y;
    }
}

__global__ void k_wcomb(const float* __restrict__ mw2, const float* __restrict__ mb2,
                        const float* __restrict__ aw1, float* wcomb, float* bcomb) {
    int o = blockIdx.x * blockDim.x + threadIdx.x;
    if (o < 64 * 64) {
        int c = o >> 6, k = o & 63;
        float s = 0.f;
        #pragma unroll 8
        for (int a = 0; a < 64; ++a) s += mw2[c * 64 + a] * aw1[(64 + a) * 64 + k];
        wcomb[o] = s;
    } else if (o < 64 * 64 + 64) {
        int k = o - 64 * 64;
        float s = 0.f;
        #pragma unroll 8
        for (int a = 0; a < 64; ++a) s += mb2[a] * aw1[(64 + a) * 64 + k];
        bcomb[k] = s;
    }
}

// ---- tiled GEMM blocks: BM=128, BN=64, thread tile 8m x 4f ----
__device__ __forceinline__ void stage_x(float* xs, const float* src, int m0) {
    int t = threadIdx.x;
    #pragma unroll
    for (int it = 0; it < 8; ++it) {
        int idx = it * 256 + t;
        int m = idx >> 4;
        int q = idx & 15;
        float4 v = make_float4(0.f, 0.f, 0.f, 0.f);
        if (m0 + m < N_NODES) v = *(const float4*)(src + (size_t)(m0 + m) * 64 + q * 4);
        *(float4*)(xs + m * XP + q * 4) = v;
    }
}

__device__ __forceinline__ void stage_w(float* ws, const float* src) {
    int t = threadIdx.x;
    #pragma unroll
    for (int it = 0; it < 4; ++it) {
        int idx = it * 256 + t;
        *(float4*)(ws + idx * 4) = *(const float4*)(src + idx * 4);
    }
}

__device__ __forceinline__ void gemm_acc(const float* xs, const float* ws,
                                         int ty, int f0, float4 acc[8]) {
    #pragma unroll 4
    for (int k4 = 0; k4 < 64; k4 += 4) {
        float4 b0 = *(const float4*)(ws + (k4 + 0) * 64 + f0);
        float4 b1 = *(const float4*)(ws + (k4 + 1) * 64 + f0);
        float4 b2 = *(const float4*)(ws + (k4 + 2) * 64 + f0);
        float4 b3 = *(const float4*)(ws + (k4 + 3) * 64 + f0);
        #pragma unroll
        for (int i = 0; i < 8; ++i) {
            float4 a = *(const float4*)(xs + (i * 16 + ty) * XP + k4);
            float4 c = acc[i];
            c.x = fmaf(a.x, b0.x, c.x); c.y = fmaf(a.x, b0.y, c.y);
            c.z = fmaf(a.x, b0.z, c.z); c.w = fmaf(a.x, b0.w, c.w);
            c.x = fmaf(a.y, b1.x, c.x); c.y = fmaf(a.y, b1.y, c.y);
            c.z = fmaf(a.y, b1.z, c.z); c.w = fmaf(a.y, b1.w, c.w);
            c.x = fmaf(a.z, b2.x, c.x); c.y = fmaf(a.z, b2.y, c.y);
            c.z = fmaf(a.z, b2.z, c.z); c.w = fmaf(a.z, b2.w, c.w);
            c.x = fmaf(a.w, b3.x, c.x); c.y = fmaf(a.w, b3.y, c.y);
            c.z = fmaf(a.w, b3.z, c.z); c.w = fmaf(a.w, b3.w, c.w);
            acc[i] = c;
        }
    }
}

// Fused: P' = x@W1a + mb1 - pos@W1p (fp32 -> d_out temp)
//        Q' = x@W1b       + pos@W1p (fp16 -> ws Q)
__global__ void __launch_bounds__(256) k_pre(const float* __restrict__ x,
                                             const float* __restrict__ pos,
                                             const float* __restrict__ mw1,
                                             const float* __restrict__ mb1,
                                             float* __restrict__ P,
                                             __half* __restrict__ Q16) {
    __shared__ float xs[128 * XP];
    __shared__ float ws[64 * 64];
    int m0 = blockIdx.x * 128;
    int t = threadIdx.x, tx = t & 15, ty = t >> 4, f0 = tx * 4;

    stage_x(xs, x, m0);
    stage_w(ws, mw1);                 // W1a
    __syncthreads();
    float4 accP[8];
    #pragma unroll
    for (int i = 0; i < 8; ++i) accP[i] = make_float4(0.f, 0.f, 0.f, 0.f);
    gemm_acc(xs, ws, ty, f0, accP);
    __syncthreads();
    stage_w(ws, mw1 + 4096);          // W1b
    __syncthreads();
    float4 accQ[8];
    #pragma unroll
    for (int i = 0; i < 8; ++i) accQ[i] = make_float4(0.f, 0.f, 0.f, 0.f);
    gemm_acc(xs, ws, ty, f0, accQ);

    float4 wpx = *(const float4*)(mw1 + 128 * 64 + f0);
    float4 wpy = *(const float4*)(mw1 + 129 * 64 + f0);
    float4 wpz = *(const float4*)(mw1 + 130 * 64 + f0);
    float4 bias = *(const float4*)(mb1 + f0);

    #pragma unroll
    for (int i = 0; i < 8; ++i) {
        int m = m0 + i * 16 + ty;
        if (m >= N_NODES) continue;
        float px = pos[3 * m], py = pos[3 * m + 1], pz = pos[3 * m + 2];
        float dx = px * wpx.x + py * wpy.x + pz * wpz.x;
        float dy = px * wpx.y + py * wpy.y + pz * wpz.y;
        float dz = px * wpx.z + py * wpy.z + pz * wpz.z;
        float dw = px * wpx.w + py * wpy.w + pz * wpz.w;
        float4 cp = accP[i];
        cp.x += bias.x - dx; cp.y += bias.y - dy;
        cp.z += bias.z - dz; cp.w += bias.w - dw;
        *(float4*)(P + (size_t)m * 64 + f0) = cp;
        float4 cq = accQ[i];
        cq.x += dx; cq.y += dy; cq.z += dz; cq.w += dw;
        uint lo = ((uint)__half_as_ushort(__float2half_rn(cq.y)) << 16)
                | (uint)__half_as_ushort(__float2half_rn(cq.x));
        uint hi = ((uint)__half_as_ushort(__float2half_rn(cq.w)) << 16)
                | (uint)__half_as_ushort(__float2half_rn(cq.z));
        *(uint2*)((unsigned short*)Q16 + (size_t)m * 64 + f0) = make_uint2(lo, hi);
    }
}

// Edge aggregation: one wave per node; hmean = mean(relu(P'_i + Q'_j)).
// Static-trip inner loop (16) -> 16 independent gathers in flight.
__global__ void __launch_bounds__(256) k_c1(const __half* __restrict__ Q16,
                                            const int* __restrict__ off,
                                            const int* __restrict__ sj,
                                            float* Phm) {
    int wave = threadIdx.x >> 6, lane = threadIdx.x & 63;
    int node = blockIdx.x * 4 + wave;
    if (node >= N_NODES) return;
    float Pv = Phm[(size_t)node * 64 + lane];
    int o0 = off[node], o1 = off[node + 1];
    int dg = o1 - o0;
    float acc = 0.f;
    for (int base = o0; base < o1; base += 64) {
        int m = min(64, o1 - base);
        int jvv = (lane < m) ? sj[base + lane] : 0;
        for (int g = 0; g < 64; g += 16) {
            if (g >= m) break;
            float v[16];
            #pragma unroll
            for (int cc = 0; cc < 16; ++cc) {
                int jc = __builtin_amdgcn_readlane(jvv, g + cc);
                v[cc] = __half2float(Q16[(size_t)jc * 64 + lane]);
            }
            #pragma unroll
            for (int cc = 0; cc < 16; ++cc) {
                float r = fmaxf(Pv + v[cc], 0.f);
                acc += (g + cc < m) ? r : 0.f;
            }
        }
    }
    Phm[(size_t)node * 64 + lane] = (dg > 0) ? acc / (float)dg : 0.f;
}

// out = relu(x@aw1_top + hm@wcomb + ab1 + [deg>0]*bcomb) @ aw2 + ab2
__global__ void __launch_bounds__(256) k_c2(const float* __restrict__ x,
                                            const float* hm_in,
                                            const float* __restrict__ aw1,
                                            const float* __restrict__ ab1,
                                            const float* __restrict__ wcomb,
                                            const float* __restrict__ bcomb,
                                            const float* __restrict__ aw2,
                                            const float* __restrict__ ab2,
                                            const int* __restrict__ deg,
                                            float* out) {
    __shared__ float xs[128 * XP];
    __shared__ float ws[64 * 64];
    int m0 = blockIdx.x * 128;
    int t = threadIdx.x, tx = t & 15, ty = t >> 4, f0 = tx * 4;
    float4 acc[8];
    #pragma unroll
    for (int i = 0; i < 8; ++i) acc[i] = make_float4(0.f, 0.f, 0.f, 0.f);

    stage_x(xs, x, m0);
    stage_w(ws, aw1);
    __syncthreads();
    gemm_acc(xs, ws, ty, f0, acc);
    __syncthreads();

    stage_x(xs, hm_in, m0);
    stage_w(ws, wcomb);
    __syncthreads();
    gemm_acc(xs, ws, ty, f0, acc);
    __syncthreads();

    float4 b1v = *(const float4*)(ab1 + f0);
    float4 bcv = *(const float4*)(bcomb + f0);
    #pragma unroll
    for (int i = 0; i < 8; ++i) {
        int m = m0 + i * 16 + ty;
        int dg = (m < N_NODES) ? deg[m] : 0;
        float4 c = acc[i];
        float bx = b1v.x, by = b1v.y, bz = b1v.z, bw = b1v.w;
        if (dg > 0) { bx += bcv.x; by += bcv.y; bz += bcv.z; bw += bcv.w; }
        c.x = fmaxf(c.x + bx, 0.f);
        c.y = fmaxf(c.y + by, 0.f);
        c.z = fmaxf(c.z + bz, 0.f);
        c.w = fmaxf(c.w + bw, 0.f);
        *(float4*)(xs + (i * 16 + ty) * XP + f0) = c;
    }
    stage_w(ws, aw2);
    __syncthreads();

    float4 a2[8];
    #pragma unroll
    for (int i = 0; i < 8; ++i) a2[i] = make_float4(0.f, 0.f, 0.f, 0.f);
    gemm_acc(xs, ws, ty, f0, a2);
    float4 b2v = *(const float4*)(ab2 + f0);
    #pragma unroll
    for (int i = 0; i < 8; ++i) {
        int m = m0 + i * 16 + ty;
        if (m < N_NODES) {
            float4 c = a2[i];
            c.x += b2v.x; c.y += b2v.y; c.z += b2v.z; c.w += b2v.w;
            *(float4*)(out + (size_t)m * 64 + f0) = c;
        }
    }
}

extern "C" void kernel_launch(void* const* d_in, const int* in_sizes, int n_in,
                              void* d_out, int out_size, void* d_ws, size_t ws_size,
                              hipStream_t stream) {
    const float* x   = (const float*)d_in[0];
    const int*   ei  = (const int*)d_in[1];
    const int*   ej  = ((const int*)d_in[1]) + N_EDGES;
    const float* pos = (const float*)d_in[2];
    const float* mw1 = (const float*)d_in[3];
    const float* mb1 = (const float*)d_in[4];
    const float* mw2 = (const float*)d_in[5];
    const float* mb2 = (const float*)d_in[6];
    const float* aw1 = (const float*)d_in[7];
    const float* ab1 = (const float*)d_in[8];
    const float* aw2 = (const float*)d_in[9];
    const float* ab2 = (const float*)d_in[10];

    char* ws = (char*)d_ws;
    int*    off    = (int*)(ws + WS_OFF);
    int*    deg    = (int*)(ws + WS_DEG);
    int*    cur    = (int*)(ws + WS_CUR);
    int*    bsum   = (int*)(ws + WS_BSUM);
    int*    pcur   = (int*)(ws + WS_PCUR);
    int*    sj     = (int*)(ws + WS_SJ);
    float*  wcomb  = (float*)(ws + WS_WCOMB);
    float*  bcomb  = (float*)(ws + WS_BCOMB);
    __half* Q16    = (__half*)(ws + WS_Q);
    int2*   binned = (int2*)(ws + WS_BIN);
    float*  out    = (float*)d_out;

    const int NB1 = (N_NODES + 255) / 256;        // 391
    const int NBT = (N_NODES + 127) / 128;        // 782
    const int NBE = (N_EDGES / 4 + 255) / 256;    // 1563
    const int NBB = (N_EDGES + 2047) / 2048;      // 782
    hipLaunchKernelGGL(k_zero,  dim3(NB1), dim3(256), 0, stream, deg);
    hipLaunchKernelGGL(k_count, dim3(NBE), dim3(256), 0, stream, ei, deg);
    hipLaunchKernelGGL(k_scan1, dim3(NB1), dim3(256), 0, stream, deg, off, bsum);
    hipLaunchKernelGGL(k_scan2, dim3(1), dim3(512), 0, stream, bsum, NB1);
    hipLaunchKernelGGL(k_scan3, dim3(NB1), dim3(256), 0, stream, deg, off, bsum, cur, pcur);
    hipLaunchKernelGGL(k_bin,   dim3(NBB), dim3(256), 0, stream, ei, ej, pcur, binned);
    hipLaunchKernelGGL(k_fill2, dim3(256), dim3(256), 0, stream, binned, off, cur, sj);
    hipLaunchKernelGGL(k_wcomb, dim3(17), dim3(256), 0, stream, mw2, mb2, aw1, wcomb, bcomb);
    hipLaunchKernelGGL(k_pre,   dim3(NBT), dim3(256), 0, stream, x, pos, mw1, mb1, out, Q16);
    hipLaunchKernelGGL(k_c1,    dim3((N_NODES + 3) / 4), dim3(256), 0, stream,
                       Q16, off, sj, out);
    hipLaunchKernelGGL(k_c2,    dim3(NBT), dim3(256), 0, stream,
                       x, out, aw1, ab1, wcomb, bcomb, aw2, ab2, deg, out);
}

// Round 9
// 220.658 us; speedup vs baseline: 1.3802x; 1.3802x over previous
//
#include <hip/hip_runtime.h>
#include <hip/hip_fp16.h>

#define N_NODES 100000
#define N_EDGES 1600000
#define NPART 98           // ceil(100000/1024) partitions of 1024 nodes
#define CAP   20480        // bucket capacity (mean 16384, sigma~127 -> 32 sigma slack)

// ---------------- workspace layout (bytes) ----------------
#define WS_OFF   0         // int[N+1]
#define WS_PCUR  400016    // int[128]
#define WS_B     400528    // int[128]
#define WS_SJ    401040    // int[E]            (6.4 MB)
#define WS_WCOMB 6801040   // float[64*64]
#define WS_BCOMB 6817424   // float[64]
#define WS_Q     6817680   // __half[N*64]      (12.8 MB)
#define WS_BIN   19617680  // int[NPART*CAP]    (8.0 MB)   total ~27.6 MB

#define XP 68   // padded LDS row pitch (floats)

__global__ void k_init0(int* pcur) {
    int t = threadIdx.x;
    if (t < NPART) pcur[t] = t * CAP;
}

// bin edges into 98 node-partition buckets; packed (i_local<<17)|j, 4B/edge.
// Only per-block aggregated global atomics (98 per block).
__global__ void __launch_bounds__(256) k_binc(const int* __restrict__ ei,
                                              const int* __restrict__ ej,
                                              int* pcur, int* __restrict__ binned) {
    __shared__ int cnt[NPART];
    __shared__ int base[NPART];
    int t = threadIdx.x;
    for (int q = t; q < NPART; q += 256) cnt[q] = 0;
    __syncthreads();

    int e0 = blockIdx.x * 2048 + t * 4;
    int e1 = e0 + 1024;
    bool v0 = e0 < N_EDGES, v1 = e1 < N_EDGES;
    int4 i0, j0, i1, j1;
    int p0[4], s0[4], p1[4], s1[4];
    if (v0) {
        i0 = *(const int4*)(ei + e0); j0 = *(const int4*)(ej + e0);
        p0[0] = i0.x >> 10; s0[0] = atomicAdd(&cnt[p0[0]], 1);
        p0[1] = i0.y >> 10; s0[1] = atomicAdd(&cnt[p0[1]], 1);
        p0[2] = i0.z >> 10; s0[2] = atomicAdd(&cnt[p0[2]], 1);
        p0[3] = i0.w >> 10; s0[3] = atomicAdd(&cnt[p0[3]], 1);
    }
    if (v1) {
        i1 = *(const int4*)(ei + e1); j1 = *(const int4*)(ej + e1);
        p1[0] = i1.x >> 10; s1[0] = atomicAdd(&cnt[p1[0]], 1);
        p1[1] = i1.y >> 10; s1[1] = atomicAdd(&cnt[p1[1]], 1);
        p1[2] = i1.z >> 10; s1[2] = atomicAdd(&cnt[p1[2]], 1);
        p1[3] = i1.w >> 10; s1[3] = atomicAdd(&cnt[p1[3]], 1);
    }
    __syncthreads();
    for (int q = t; q < NPART; q += 256)
        base[q] = cnt[q] ? atomicAdd(&pcur[q], cnt[q]) : 0;
    __syncthreads();
    if (v0) {
        int a;
        a = base[p0[0]] + s0[0]; if (a < (p0[0] + 1) * CAP) binned[a] = ((i0.x & 1023) << 17) | j0.x;
        a = base[p0[1]] + s0[1]; if (a < (p0[1] + 1) * CAP) binned[a] = ((i0.y & 1023) << 17) | j0.y;
        a = base[p0[2]] + s0[2]; if (a < (p0[2] + 1) * CAP) binned[a] = ((i0.z & 1023) << 17) | j0.z;
        a = base[p0[3]] + s0[3]; if (a < (p0[3] + 1) * CAP) binned[a] = ((i0.w & 1023) << 17) | j0.w;
    }
    if (v1) {
        int a;
        a = base[p1[0]] + s1[0]; if (a < (p1[0] + 1) * CAP) binned[a] = ((i1.x & 1023) << 17) | j1.x;
        a = base[p1[1]] + s1[1]; if (a < (p1[1] + 1) * CAP) binned[a] = ((i1.y & 1023) << 17) | j1.y;
        a = base[p1[2]] + s1[2]; if (a < (p1[2] + 1) * CAP) binned[a] = ((i1.z & 1023) << 17) | j1.z;
        a = base[p1[3]] + s1[3]; if (a < (p1[3] + 1) * CAP) binned[a] = ((i1.w & 1023) << 17) | j1.w;
    }
}

// exclusive prefix over bucket counts -> global CSR bucket bases
__global__ void k_scanB(const int* __restrict__ pcur, int* B) {
    __shared__ int s[128];
    int t = threadIdx.x;
    int c = 0;
    if (t < NPART) c = min(pcur[t] - t * CAP, CAP);
    s[t] = c;
    __syncthreads();
    for (int o = 1; o < 128; o <<= 1) {
        int a = (t >= o) ? s[t - o] : 0;
        __syncthreads();
        s[t] += a;
        __syncthreads();
    }
    if (t < NPART) B[t] = s[t] - c;
    if (t == NPART - 1) B[NPART] = s[t];
}

// per-partition counting sort: LDS histogram -> LDS scan -> off[] + sj scatter.
// No global atomics at all.
__global__ void __launch_bounds__(256) k_fill3(const int* __restrict__ binned,
                                               const int* __restrict__ B,
                                               int* __restrict__ off,
                                               int* __restrict__ sj) {
    __shared__ int hist[1024];
    __shared__ int tsum[256];
    int p = blockIdx.x, t = threadIdx.x;
    int b0g = B[p];
    int cnt_p = B[p + 1] - b0g;
    const int* src = binned + p * CAP;

    #pragma unroll
    for (int q = 0; q < 4; ++q) hist[t * 4 + q] = 0;
    __syncthreads();
    for (int e = t; e < cnt_p; e += 256) atomicAdd(&hist[src[e] >> 17], 1);
    __syncthreads();

    // exclusive scan over 1024 histogram entries
    int b0 = hist[t * 4], b1 = hist[t * 4 + 1], b2 = hist[t * 4 + 2], b3 = hist[t * 4 + 3];
    int c1 = b0, c2 = c1 + b1, c3 = c2 + b2, tot = c3 + b3;
    tsum[t] = tot;
    __syncthreads();
    for (int o = 1; o < 256; o <<= 1) {
        int a = (t >= o) ? tsum[t - o] : 0;
        __syncthreads();
        tsum[t] += a;
        __syncthreads();
    }
    int tex = tsum[t] - tot;
    hist[t * 4]     = tex;
    hist[t * 4 + 1] = tex + c1;
    hist[t * 4 + 2] = tex + c2;
    hist[t * 4 + 3] = tex + c3;
    __syncthreads();

    int lo = p * 1024;
    #pragma unroll
    for (int q = 0; q < 4; ++q) {
        int n = t * 4 + q, g = lo + n;
        if (g < N_NODES) off[g] = b0g + hist[n];
    }
    if (p == NPART - 1 && t == 0) off[N_NODES] = B[NPART];
    __syncthreads();

    for (int e = t; e < cnt_p; e += 256) {
        int v = src[e];
        int slot = atomicAdd(&hist[v >> 17], 1);   // LDS atomic
        sj[b0g + slot] = v & 0x1FFFF;
    }
}

__global__ void k_wcomb(const float* __restrict__ mw2, const float* __restrict__ mb2,
                        const float* __restrict__ aw1, float* wcomb, float* bcomb) {
    int o = blockIdx.x * blockDim.x + threadIdx.x;
    if (o < 64 * 64) {
        int c = o >> 6, k = o & 63;
        float s = 0.f;
        #pragma unroll 8
        for (int a = 0; a < 64; ++a) s += mw2[c * 64 + a] * aw1[(64 + a) * 64 + k];
        wcomb[o] = s;
    } else if (o < 64 * 64 + 64) {
        int k = o - 64 * 64;
        float s = 0.f;
        #pragma unroll 8
        for (int a = 0; a < 64; ++a) s += mb2[a] * aw1[(64 + a) * 64 + k];
        bcomb[k] = s;
    }
}

// ---- tiled GEMM blocks: BM=128, BN=64, thread tile 8m x 4f ----
__device__ __forceinline__ void stage_x(float* xs, const float* src, int m0) {
    int t = threadIdx.x;
    #pragma unroll
    for (int it = 0; it < 8; ++it) {
        int idx = it * 256 + t;
        int m = idx >> 4;
        int q = idx & 15;
        float4 v = make_float4(0.f, 0.f, 0.f, 0.f);
        if (m0 + m < N_NODES) v = *(const float4*)(src + (size_t)(m0 + m) * 64 + q * 4);
        *(float4*)(xs + m * XP + q * 4) = v;
    }
}

__device__ __forceinline__ void stage_w(float* ws, const float* src) {
    int t = threadIdx.x;
    #pragma unroll
    for (int it = 0; it < 4; ++it) {
        int idx = it * 256 + t;
        *(float4*)(ws + idx * 4) = *(const float4*)(src + idx * 4);
    }
}

__device__ __forceinline__ void gemm_acc(const float* xs, const float* ws,
                                         int ty, int f0, float4 acc[8]) {
    #pragma unroll 4
    for (int k4 = 0; k4 < 64; k4 += 4) {
        float4 b0 = *(const float4*)(ws + (k4 + 0) * 64 + f0);
        float4 b1 = *(const float4*)(ws + (k4 + 1) * 64 + f0);
        float4 b2 = *(const float4*)(ws + (k4 + 2) * 64 + f0);
        float4 b3 = *(const float4*)(ws + (k4 + 3) * 64 + f0);
        #pragma unroll
        for (int i = 0; i < 8; ++i) {
            float4 a = *(const float4*)(xs + (i * 16 + ty) * XP + k4);
            float4 c = acc[i];
            c.x = fmaf(a.x, b0.x, c.x); c.y = fmaf(a.x, b0.y, c.y);
            c.z = fmaf(a.x, b0.z, c.z); c.w = fmaf(a.x, b0.w, c.w);
            c.x = fmaf(a.y, b1.x, c.x); c.y = fmaf(a.y, b1.y, c.y);
            c.z = fmaf(a.y, b1.z, c.z); c.w = fmaf(a.y, b1.w, c.w);
            c.x = fmaf(a.z, b2.x, c.x); c.y = fmaf(a.z, b2.y, c.y);
            c.z = fmaf(a.z, b2.z, c.z); c.w = fmaf(a.z, b2.w, c.w);
            c.x = fmaf(a.w, b3.x, c.x); c.y = fmaf(a.w, b3.y, c.y);
            c.z = fmaf(a.w, b3.z, c.z); c.w = fmaf(a.w, b3.w, c.w);
            acc[i] = c;
        }
    }
}

// Fused: P' = x@W1a + mb1 - pos@W1p (fp32 -> d_out temp)
//        Q' = x@W1b       + pos@W1p (fp16 -> ws Q)
__global__ void __launch_bounds__(256) k_pre(const float* __restrict__ x,
                                             const float* __restrict__ pos,
                                             const float* __restrict__ mw1,
                                             const float* __restrict__ mb1,
                                             float* __restrict__ P,
                                             __half* __restrict__ Q16) {
    __shared__ float xs[128 * XP];
    __shared__ float ws[64 * 64];
    int m0 = blockIdx.x * 128;
    int t = threadIdx.x, tx = t & 15, ty = t >> 4, f0 = tx * 4;

    stage_x(xs, x, m0);
    stage_w(ws, mw1);                 // W1a
    __syncthreads();
    float4 accP[8];
    #pragma unroll
    for (int i = 0; i < 8; ++i) accP[i] = make_float4(0.f, 0.f, 0.f, 0.f);
    gemm_acc(xs, ws, ty, f0, accP);
    __syncthreads();
    stage_w(ws, mw1 + 4096);          // W1b
    __syncthreads();
    float4 accQ[8];
    #pragma unroll
    for (int i = 0; i < 8; ++i) accQ[i] = make_float4(0.f, 0.f, 0.f, 0.f);
    gemm_acc(xs, ws, ty, f0, accQ);

    float4 wpx = *(const float4*)(mw1 + 128 * 64 + f0);
    float4 wpy = *(const float4*)(mw1 + 129 * 64 + f0);
    float4 wpz = *(const float4*)(mw1 + 130 * 64 + f0);
    float4 bias = *(const float4*)(mb1 + f0);

    #pragma unroll
    for (int i = 0; i < 8; ++i) {
        int m = m0 + i * 16 + ty;
        if (m >= N_NODES) continue;
        float px = pos[3 * m], py = pos[3 * m + 1], pz = pos[3 * m + 2];
        float dx = px * wpx.x + py * wpy.x + pz * wpz.x;
        float dy = px * wpx.y + py * wpy.y + pz * wpz.y;
        float dz = px * wpx.z + py * wpy.z + pz * wpz.z;
        float dw = px * wpx.w + py * wpy.w + pz * wpz.w;
        float4 cp = accP[i];
        cp.x += bias.x - dx; cp.y += bias.y - dy;
        cp.z += bias.z - dz; cp.w += bias.w - dw;
        *(float4*)(P + (size_t)m * 64 + f0) = cp;
        float4 cq = accQ[i];
        cq.x += dx; cq.y += dy; cq.z += dz; cq.w += dw;
        uint lo = ((uint)__half_as_ushort(__float2half_rn(cq.y)) << 16)
                | (uint)__half_as_ushort(__float2half_rn(cq.x));
        uint hi = ((uint)__half_as_ushort(__float2half_rn(cq.w)) << 16)
                | (uint)__half_as_ushort(__float2half_rn(cq.z));
        *(uint2*)((unsigned short*)Q16 + (size_t)m * 64 + f0) = make_uint2(lo, hi);
    }
}

// Edge aggregation: one wave per node; hmean = mean(relu(P'_i + Q'_j)).
// Static-trip inner loop (16) -> 16 independent gathers in flight.
__global__ void __launch_bounds__(256) k_c1(const __half* __restrict__ Q16,
                                            const int* __restrict__ off,
                                            const int* __restrict__ sj,
                                            float* Phm) {
    int wave = threadIdx.x >> 6, lane = threadIdx.x & 63;
    int node = blockIdx.x * 4 + wave;
    if (node >= N_NODES) return;
    float Pv = Phm[(size_t)node * 64 + lane];
    int o0 = off[node], o1 = off[node + 1];
    int dg = o1 - o0;
    float acc = 0.f;
    for (int base = o0; base < o1; base += 64) {
        int m = min(64, o1 - base);
        int jvv = (lane < m) ? sj[base + lane] : 0;
        for (int g = 0; g < 64; g += 16) {
            if (g >= m) break;
            float v[16];
            #pragma unroll
            for (int cc = 0; cc < 16; ++cc) {
                int jc = __builtin_amdgcn_readlane(jvv, g + cc);
                v[cc] = __half2float(Q16[(size_t)jc * 64 + lane]);
            }
            #pragma unroll
            for (int cc = 0; cc < 16; ++cc) {
                float r = fmaxf(Pv + v[cc], 0.f);
                acc += (g + cc < m) ? r : 0.f;
            }
        }
    }
    Phm[(size_t)node * 64 + lane] = (dg > 0) ? acc / (float)dg : 0.f;
}

// out = relu(x@aw1_top + hm@wcomb + ab1 + [deg>0]*bcomb) @ aw2 + ab2
__global__ void __launch_bounds__(256) k_c2(const float* __restrict__ x,
                                            const float* hm_in,
                                            const float* __restrict__ aw1,
                                            const float* __restrict__ ab1,
                                            const float* __restrict__ wcomb,
                                            const float* __restrict__ bcomb,
                                            const float* __restrict__ aw2,
                                            const float* __restrict__ ab2,
                                            const int* __restrict__ off,
                                            float* out) {
    __shared__ float xs[128 * XP];
    __shared__ float ws[64 * 64];
    int m0 = blockIdx.x * 128;
    int t = threadIdx.x, tx = t & 15, ty = t >> 4, f0 = tx * 4;
    float4 acc[8];
    #pragma unroll
    for (int i = 0; i < 8; ++i) acc[i] = make_float4(0.f, 0.f, 0.f, 0.f);

    stage_x(xs, x, m0);
    stage_w(ws, aw1);
    __syncthreads();
    gemm_acc(xs, ws, ty, f0, acc);
    __syncthreads();

    stage_x(xs, hm_in, m0);
    stage_w(ws, wcomb);
    __syncthreads();
    gemm_acc(xs, ws, ty, f0, acc);
    __syncthreads();

    float4 b1v = *(const float4*)(ab1 + f0);
    float4 bcv = *(const float4*)(bcomb + f0);
    #pragma unroll
    for (int i = 0; i < 8; ++i) {
        int m = m0 + i * 16 + ty;
        int dg = (m < N_NODES) ? (off[m + 1] - off[m]) : 0;
        float4 c = acc[i];
        float bx = b1v.x, by = b1v.y, bz = b1v.z, bw = b1v.w;
        if (dg > 0) { bx += bcv.x; by += bcv.y; bz += bcv.z; bw += bcv.w; }
        c.x = fmaxf(c.x + bx, 0.f);
        c.y = fmaxf(c.y + by, 0.f);
        c.z = fmaxf(c.z + bz, 0.f);
        c.w = fmaxf(c.w + bw, 0.f);
        *(float4*)(xs + (i * 16 + ty) * XP + f0) = c;
    }
    stage_w(ws, aw2);
    __syncthreads();

    float4 a2[8];
    #pragma unroll
    for (int i = 0; i < 8; ++i) a2[i] = make_float4(0.f, 0.f, 0.f, 0.f);
    gemm_acc(xs, ws, ty, f0, a2);
    float4 b2v = *(const float4*)(ab2 + f0);
    #pragma unroll
    for (int i = 0; i < 8; ++i) {
        int m = m0 + i * 16 + ty;
        if (m < N_NODES) {
            float4 c = a2[i];
            c.x += b2v.x; c.y += b2v.y; c.z += b2v.z; c.w += b2v.w;
            *(float4*)(out + (size_t)m * 64 + f0) = c;
        }
    }
}

extern "C" void kernel_launch(void* const* d_in, const int* in_sizes, int n_in,
                              void* d_out, int out_size, void* d_ws, size_t ws_size,
                              hipStream_t stream) {
    const float* x   = (const float*)d_in[0];
    const int*   ei  = (const int*)d_in[1];
    const int*   ej  = ((const int*)d_in[1]) + N_EDGES;
    const float* pos = (const float*)d_in[2];
    const float* mw1 = (const float*)d_in[3];
    const float* mb1 = (const float*)d_in[4];
    const float* mw2 = (const float*)d_in[5];
    const float* mb2 = (const float*)d_in[6];
    const float* aw1 = (const float*)d_in[7];
    const float* ab1 = (const float*)d_in[8];
    const float* aw2 = (const float*)d_in[9];
    const float* ab2 = (const float*)d_in[10];

    char* ws = (char*)d_ws;
    int*    off    = (int*)(ws + WS_OFF);
    int*    pcur   = (int*)(ws + WS_PCUR);
    int*    B      = (int*)(ws + WS_B);
    int*    sj     = (int*)(ws + WS_SJ);
    float*  wcomb  = (float*)(ws + WS_WCOMB);
    float*  bcomb  = (float*)(ws + WS_BCOMB);
    __half* Q16    = (__half*)(ws + WS_Q);
    int*    binned = (int*)(ws + WS_BIN);
    float*  out    = (float*)d_out;

    const int NBT = (N_NODES + 127) / 128;        // 782
    const int NBB = (N_EDGES + 2047) / 2048;      // 782
    hipLaunchKernelGGL(k_init0, dim3(1), dim3(128), 0, stream, pcur);
    hipLaunchKernelGGL(k_binc,  dim3(NBB), dim3(256), 0, stream, ei, ej, pcur, binned);
    hipLaunchKernelGGL(k_scanB, dim3(1), dim3(128), 0, stream, pcur, B);
    hipLaunchKernelGGL(k_fill3, dim3(NPART), dim3(256), 0, stream, binned, B, off, sj);
    hipLaunchKernelGGL(k_wcomb, dim3(17), dim3(256), 0, stream, mw2, mb2, aw1, wcomb, bcomb);
    hipLaunchKernelGGL(k_pre,   dim3(NBT), dim3(256), 0, stream, x, pos, mw1, mb1, out, Q16);
    hipLaunchKernelGGL(k_c1,    dim3((N_NODES + 3) / 4), dim3(256), 0, stream,
                       Q16, off, sj, out);
    hipLaunchKernelGGL(k_c2,    dim3(NBT), dim3(256), 0, stream,
                       x, out, aw1, ab1, wcomb, bcomb, aw2, ab2, off, out);
}

// Round 10
// 178.504 us; speedup vs baseline: 1.7062x; 1.2362x over previous
//
#include <hip/hip_runtime.h>
#include <hip/hip_fp16.h>

#define N_NODES 100000
#define N_EDGES 1600000
#define NPART 98           // partitions of 1024 nodes
#define CAP   20480        // bucket capacity

typedef _Float16 half8 __attribute__((ext_vector_type(8)));
typedef float f32x4 __attribute__((ext_vector_type(4)));

// ---------------- workspace layout (bytes) ----------------
#define WS_OFF   0          // int[N+1]
#define WS_PCUR  400016     // int[128]
#define WS_B     400528     // int[128]
#define WS_SJ    401040     // int[E]           (6.4 MB)
#define WS_WCOMB 6801040    // float[64*64]
#define WS_BCOMB 6817424    // float[64]
#define WS_PK    6817680    // _Float16[5*4096] (40 KB) B-frag packed weights
#define WS_Q     6858640    // _Float16[N*64]   (12.8 MB)
#define WS_BIN   19658640   // int[NPART*CAP] (8MB) OVERLAPS hm16 (12.8MB) - disjoint lifetimes
#define WS_HM16  19658640   // _Float16[N*64]

__global__ void k_init0(int* pcur) {
    int t = threadIdx.x;
    if (t < NPART) pcur[t] = t * CAP;
}

// bin edges into 98 node-partition buckets; packed (i_local<<17)|j.
__global__ void __launch_bounds__(256) k_binc(const int* __restrict__ ei,
                                              const int* __restrict__ ej,
                                              int* pcur, int* __restrict__ binned) {
    __shared__ int cnt[NPART];
    __shared__ int base[NPART];
    int t = threadIdx.x;
    for (int q = t; q < NPART; q += 256) cnt[q] = 0;
    __syncthreads();

    int e0 = blockIdx.x * 2048 + t * 4;
    int e1 = e0 + 1024;
    bool v0 = e0 < N_EDGES, v1 = e1 < N_EDGES;
    int4 i0, j0, i1, j1;
    int p0[4], s0[4], p1[4], s1[4];
    if (v0) {
        i0 = *(const int4*)(ei + e0); j0 = *(const int4*)(ej + e0);
        p0[0] = i0.x >> 10; s0[0] = atomicAdd(&cnt[p0[0]], 1);
        p0[1] = i0.y >> 10; s0[1] = atomicAdd(&cnt[p0[1]], 1);
        p0[2] = i0.z >> 10; s0[2] = atomicAdd(&cnt[p0[2]], 1);
        p0[3] = i0.w >> 10; s0[3] = atomicAdd(&cnt[p0[3]], 1);
    }
    if (v1) {
        i1 = *(const int4*)(ei + e1); j1 = *(const int4*)(ej + e1);
        p1[0] = i1.x >> 10; s1[0] = atomicAdd(&cnt[p1[0]], 1);
        p1[1] = i1.y >> 10; s1[1] = atomicAdd(&cnt[p1[1]], 1);
        p1[2] = i1.z >> 10; s1[2] = atomicAdd(&cnt[p1[2]], 1);
        p1[3] = i1.w >> 10; s1[3] = atomicAdd(&cnt[p1[3]], 1);
    }
    __syncthreads();
    for (int q = t; q < NPART; q += 256)
        base[q] = cnt[q] ? atomicAdd(&pcur[q], cnt[q]) : 0;
    __syncthreads();
    if (v0) {
        int a;
        a = base[p0[0]] + s0[0]; if (a < (p0[0] + 1) * CAP) binned[a] = ((i0.x & 1023) << 17) | j0.x;
        a = base[p0[1]] + s0[1]; if (a < (p0[1] + 1) * CAP) binned[a] = ((i0.y & 1023) << 17) | j0.y;
        a = base[p0[2]] + s0[2]; if (a < (p0[2] + 1) * CAP) binned[a] = ((i0.z & 1023) << 17) | j0.z;
        a = base[p0[3]] + s0[3]; if (a < (p0[3] + 1) * CAP) binned[a] = ((i0.w & 1023) << 17) | j0.w;
    }
    if (v1) {
        int a;
        a = base[p1[0]] + s1[0]; if (a < (p1[0] + 1) * CAP) binned[a] = ((i1.x & 1023) << 17) | j1.x;
        a = base[p1[1]] + s1[1]; if (a < (p1[1] + 1) * CAP) binned[a] = ((i1.y & 1023) << 17) | j1.y;
        a = base[p1[2]] + s1[2]; if (a < (p1[2] + 1) * CAP) binned[a] = ((i1.z & 1023) << 17) | j1.z;
        a = base[p1[3]] + s1[3]; if (a < (p1[3] + 1) * CAP) binned[a] = ((i1.w & 1023) << 17) | j1.w;
    }
}

__global__ void k_scanB(const int* __restrict__ pcur, int* B) {
    __shared__ int s[128];
    int t = threadIdx.x;
    int c = 0;
    if (t < NPART) c = min(pcur[t] - t * CAP, CAP);
    s[t] = c;
    __syncthreads();
    for (int o = 1; o < 128; o <<= 1) {
        int a = (t >= o) ? s[t - o] : 0;
        __syncthreads();
        s[t] += a;
        __syncthreads();
    }
    if (t < NPART) B[t] = s[t] - c;
    if (t == NPART - 1) B[NPART] = s[t];
}

// per-partition counting sort: LDS histogram -> off[] + sj scatter. No global atomics.
__global__ void __launch_bounds__(256) k_fill3(const int* __restrict__ binned,
                                               const int* __restrict__ B,
                                               int* __restrict__ off,
                                               int* __restrict__ sj) {
    __shared__ int hist[1024];
    __shared__ int tsum[256];
    int p = blockIdx.x, t = threadIdx.x;
    int b0g = B[p];
    int cnt_p = B[p + 1] - b0g;
    const int* src = binned + p * CAP;

    #pragma unroll
    for (int q = 0; q < 4; ++q) hist[t * 4 + q] = 0;
    __syncthreads();
    for (int e = t; e < cnt_p; e += 256) atomicAdd(&hist[src[e] >> 17], 1);
    __syncthreads();

    int b0 = hist[t * 4], b1 = hist[t * 4 + 1], b2 = hist[t * 4 + 2], b3 = hist[t * 4 + 3];
    int c1 = b0, c2 = c1 + b1, c3 = c2 + b2, tot = c3 + b3;
    tsum[t] = tot;
    __syncthreads();
    for (int o = 1; o < 256; o <<= 1) {
        int a = (t >= o) ? tsum[t - o] : 0;
        __syncthreads();
        tsum[t] += a;
        __syncthreads();
    }
    int tex = tsum[t] - tot;
    hist[t * 4]     = tex;
    hist[t * 4 + 1] = tex + c1;
    hist[t * 4 + 2] = tex + c2;
    hist[t * 4 + 3] = tex + c3;
    __syncthreads();

    int lo = p * 1024;
    #pragma unroll
    for (int q = 0; q < 4; ++q) {
        int n = t * 4 + q, g = lo + n;
        if (g < N_NODES) off[g] = b0g + hist[n];
    }
    if (p == NPART - 1 && t == 0) off[N_NODES] = B[NPART];
    __syncthreads();

    for (int e = t; e < cnt_p; e += 256) {
        int v = src[e];
        int slot = atomicAdd(&hist[v >> 17], 1);
        sj[b0g + slot] = v & 0x1FFFF;
    }
}

__global__ void k_wcomb(const float* __restrict__ mw2, const float* __restrict__ mb2,
                        const float* __restrict__ aw1, float* wcomb, float* bcomb) {
    int o = blockIdx.x * blockDim.x + threadIdx.x;
    if (o < 64 * 64) {
        int c = o >> 6, k = o & 63;
        float s = 0.f;
        #pragma unroll 8
        for (int a = 0; a < 64; ++a) s += mw2[c * 64 + a] * aw1[(64 + a) * 64 + k];
        wcomb[o] = s;
    } else if (o < 64 * 64 + 64) {
        int k = o - 64 * 64;
        float s = 0.f;
        #pragma unroll 8
        for (int a = 0; a < 64; ++a) s += mb2[a] * aw1[(64 + a) * 64 + k];
        bcomb[k] = s;
    }
}

// Pack 5 weight matrices into MFMA B-fragment order:
// pk[mat][((nt*2+kg)*64 + lane)*8 + b] = W[kg*32+(lane>>4)*8+b][nt*16+(lane&15)]
// mats: 0=W1a(mw1), 1=W1b(mw1+4096), 2=aw1_top(aw1), 3=wcomb, 4=aw2
__global__ void k_wpack(const float* __restrict__ mw1, const float* __restrict__ aw1,
                        const float* __restrict__ wcomb, const float* __restrict__ aw2,
                        _Float16* __restrict__ pk) {
    int mat = blockIdx.x;
    const float* src = (mat == 0) ? mw1 : (mat == 1) ? (mw1 + 4096)
                     : (mat == 2) ? aw1 : (mat == 3) ? wcomb : aw2;
    _Float16* dst = pk + mat * 4096;
    for (int t = threadIdx.x; t < 4096; t += 256) {
        int b_ = t & 7, l = (t >> 3) & 63, z = t >> 9;
        int kg = z & 1, nt = z >> 1;
        int k = kg * 32 + ((l >> 4) << 3) + b_;
        int n = nt * 16 + (l & 15);
        dst[t] = (_Float16)src[k * 64 + n];
    }
}

// ---- MFMA helpers ----
// A-frag (16x32 fp16): lane holds A[l&15][kg*32 + (l>>4)*8 + 0..7]
__device__ __forceinline__ half8 afrag_f32(const float* src, int row, int kg, int l) {
    const float* p = src + (size_t)row * 64 + kg * 32 + ((l >> 4) << 3);
    float4 u = *(const float4*)p;
    float4 v = *(const float4*)(p + 4);
    half8 h;
    h[0] = (_Float16)u.x; h[1] = (_Float16)u.y; h[2] = (_Float16)u.z; h[3] = (_Float16)u.w;
    h[4] = (_Float16)v.x; h[5] = (_Float16)v.y; h[6] = (_Float16)v.z; h[7] = (_Float16)v.w;
    return h;
}

// Fused: P' = x@W1a + mb1 - pos@W1p (fp32 -> d_out temp)
//        Q' = x@W1b       + pos@W1p (fp16)
// MFMA: 4 waves/block, each wave 2 strips of 16 rows (128 rows/block).
__global__ void __launch_bounds__(256) k_pre(const float* __restrict__ x,
                                             const float* __restrict__ pos,
                                             const float* __restrict__ mw1,
                                             const float* __restrict__ mb1,
                                             const _Float16* __restrict__ pk,
                                             float* __restrict__ P,
                                             _Float16* __restrict__ Q16) {
    int w = threadIdx.x >> 6, l = threadIdx.x & 63;
    int m0 = blockIdx.x * 128 + w * 32;

    half8 a[2][2];
    #pragma unroll
    for (int s = 0; s < 2; ++s)
        #pragma unroll
        for (int kg = 0; kg < 2; ++kg) {
            int row = m0 + s * 16 + (l & 15);
            if (row >= N_NODES) row = N_NODES - 1;
            a[s][kg] = afrag_f32(x, row, kg, l);
        }

    f32x4 z = {0.f, 0.f, 0.f, 0.f};
    f32x4 accP[2][4], accQ[2][4];
    #pragma unroll
    for (int s = 0; s < 2; ++s)
        #pragma unroll
        for (int nt = 0; nt < 4; ++nt) { accP[s][nt] = z; accQ[s][nt] = z; }

    #pragma unroll
    for (int nt = 0; nt < 4; ++nt)
        #pragma unroll
        for (int kg = 0; kg < 2; ++kg) {
            half8 b = *(const half8*)(pk + ((nt * 2 + kg) * 64 + l) * 8);
            accP[0][nt] = __builtin_amdgcn_mfma_f32_16x16x32_f16(a[0][kg], b, accP[0][nt], 0, 0, 0);
            accP[1][nt] = __builtin_amdgcn_mfma_f32_16x16x32_f16(a[1][kg], b, accP[1][nt], 0, 0, 0);
        }
    const _Float16* pkb = pk + 4096;
    #pragma unroll
    for (int nt = 0; nt < 4; ++nt)
        #pragma unroll
        for (int kg = 0; kg < 2; ++kg) {
            half8 b = *(const half8*)(pkb + ((nt * 2 + kg) * 64 + l) * 8);
            accQ[0][nt] = __builtin_amdgcn_mfma_f32_16x16x32_f16(a[0][kg], b, accQ[0][nt], 0, 0, 0);
            accQ[1][nt] = __builtin_amdgcn_mfma_f32_16x16x32_f16(a[1][kg], b, accQ[1][nt], 0, 0, 0);
        }

    // epilogue: C layout col=lane&15, row=(lane>>4)*4+reg
    int col = l & 15;
    float wx[4], wy[4], wz[4], bb[4];
    #pragma unroll
    for (int nt = 0; nt < 4; ++nt) {
        int n = nt * 16 + col;
        wx[nt] = mw1[128 * 64 + n];
        wy[nt] = mw1[129 * 64 + n];
        wz[nt] = mw1[130 * 64 + n];
        bb[nt] = mb1[n];
    }
    #pragma unroll
    for (int s = 0; s < 2; ++s)
        #pragma unroll
        for (int r = 0; r < 4; ++r) {
            int m = m0 + s * 16 + ((l >> 4) << 2) + r;
            if (m >= N_NODES) continue;
            float px = pos[3 * m], py = pos[3 * m + 1], pz = pos[3 * m + 2];
            #pragma unroll
            for (int nt = 0; nt < 4; ++nt) {
                int n = nt * 16 + col;
                float pd = px * wx[nt] + py * wy[nt] + pz * wz[nt];
                P[(size_t)m * 64 + n] = accP[s][nt][r] + bb[nt] - pd;
                Q16[(size_t)m * 64 + n] = (_Float16)(accQ[s][nt][r] + pd);
            }
        }
}

// Edge aggregation: hmean = mean(relu(P'_i + Q'_j)) -> fp16
__global__ void __launch_bounds__(256) k_c1(const _Float16* __restrict__ Q16,
                                            const int* __restrict__ off,
                                            const int* __restrict__ sj,
                                            const float* __restrict__ Phm,
                                            _Float16* __restrict__ hm16) {
    int wave = threadIdx.x >> 6, lane = threadIdx.x & 63;
    int node = blockIdx.x * 4 + wave;
    if (node >= N_NODES) return;
    float Pv = Phm[(size_t)node * 64 + lane];
    int o0 = off[node], o1 = off[node + 1];
    int dg = o1 - o0;
    float acc = 0.f;
    for (int base = o0; base < o1; base += 64) {
        int m = min(64, o1 - base);
        int jvv = (lane < m) ? sj[base + lane] : 0;
        for (int g = 0; g < 64; g += 16) {
            if (g >= m) break;
            float v[16];
            #pragma unroll
            for (int cc = 0; cc < 16; ++cc) {
                int jc = __builtin_amdgcn_readlane(jvv, g + cc);
                v[cc] = (float)Q16[(size_t)jc * 64 + lane];
            }
            #pragma unroll
            for (int cc = 0; cc < 16; ++cc) {
                float r = fmaxf(Pv + v[cc], 0.f);
                acc += (g + cc < m) ? r : 0.f;
            }
        }
    }
    hm16[(size_t)node * 64 + lane] = (_Float16)((dg > 0) ? acc / (float)dg : 0.f);
}

// out = relu(x@aw1t + hm@wcomb + ab1 + [deg>0]*bcomb) @ aw2 + ab2   (MFMA)
__global__ void __launch_bounds__(256) k_c2(const float* __restrict__ x,
                                            const _Float16* __restrict__ hm16,
                                            const _Float16* __restrict__ pk,
                                            const float* __restrict__ ab1,
                                            const float* __restrict__ bcomb,
                                            const float* __restrict__ ab2,
                                            const int* __restrict__ off,
                                            float* __restrict__ out) {
    __shared__ _Float16 lsh[4][2][16][64];   // per-wave h2 transpose staging
    int w = threadIdx.x >> 6, l = threadIdx.x & 63;
    int m0 = blockIdx.x * 128 + w * 32;
    int col = l & 15;

    f32x4 z = {0.f, 0.f, 0.f, 0.f};
    f32x4 acc[2][4];
    #pragma unroll
    for (int s = 0; s < 2; ++s)
        #pragma unroll
        for (int nt = 0; nt < 4; ++nt) acc[s][nt] = z;

    // phase 1: x @ aw1_top  (pk + 2*4096)
    {
        half8 a[2][2];
        #pragma unroll
        for (int s = 0; s < 2; ++s)
            #pragma unroll
            for (int kg = 0; kg < 2; ++kg) {
                int row = m0 + s * 16 + (l & 15);
                if (row >= N_NODES) row = N_NODES - 1;
                a[s][kg] = afrag_f32(x, row, kg, l);
            }
        const _Float16* pk1 = pk + 2 * 4096;
        #pragma unroll
        for (int nt = 0; nt < 4; ++nt)
            #pragma unroll
            for (int kg = 0; kg < 2; ++kg) {
                half8 b = *(const half8*)(pk1 + ((nt * 2 + kg) * 64 + l) * 8);
                acc[0][nt] = __builtin_amdgcn_mfma_f32_16x16x32_f16(a[0][kg], b, acc[0][nt], 0, 0, 0);
                acc[1][nt] = __builtin_amdgcn_mfma_f32_16x16x32_f16(a[1][kg], b, acc[1][nt], 0, 0, 0);
            }
    }
    // phase 2: + hm @ wcomb  (pk + 3*4096); hm16 is fp16, direct 16B A-frag loads
    {
        half8 a[2][2];
        #pragma unroll
        for (int s = 0; s < 2; ++s)
            #pragma unroll
            for (int kg = 0; kg < 2; ++kg) {
                int row = m0 + s * 16 + (l & 15);
                if (row >= N_NODES) row = N_NODES - 1;
                a[s][kg] = *(const half8*)(hm16 + (size_t)row * 64 + kg * 32 + ((l >> 4) << 3));
            }
        const _Float16* pk2 = pk + 3 * 4096;
        #pragma unroll
        for (int nt = 0; nt < 4; ++nt)
            #pragma unroll
            for (int kg = 0; kg < 2; ++kg) {
                half8 b = *(const half8*)(pk2 + ((nt * 2 + kg) * 64 + l) * 8);
                acc[0][nt] = __builtin_amdgcn_mfma_f32_16x16x32_f16(a[0][kg], b, acc[0][nt], 0, 0, 0);
                acc[1][nt] = __builtin_amdgcn_mfma_f32_16x16x32_f16(a[1][kg], b, acc[1][nt], 0, 0, 0);
            }
    }

    // bias + relu -> h2 fp16 into LDS (XOR-swizzled cols, 16B granule)
    float a1n[4], bcn[4];
    #pragma unroll
    for (int nt = 0; nt < 4; ++nt) {
        int n = nt * 16 + col;
        a1n[nt] = ab1[n];
        bcn[nt] = bcomb[n];
    }
    #pragma unroll
    for (int s = 0; s < 2; ++s)
        #pragma unroll
        for (int r = 0; r < 4; ++r) {
            int row = ((l >> 4) << 2) + r;
            int m = m0 + s * 16 + row;
            int dg = (m < N_NODES) ? (off[m + 1] - off[m]) : 0;
            #pragma unroll
            for (int nt = 0; nt < 4; ++nt) {
                int n = nt * 16 + col;
                float v = acc[s][nt][r] + a1n[nt] + ((dg > 0) ? bcn[nt] : 0.f);
                v = fmaxf(v, 0.f);
                lsh[w][s][row][n ^ ((row & 7) << 3)] = (_Float16)v;
            }
        }
    __syncthreads();

    // phase 3: h2 @ aw2  (pk + 4*4096); A-frags from swizzled LDS
    f32x4 acc2[2][4];
    #pragma unroll
    for (int s = 0; s < 2; ++s)
        #pragma unroll
        for (int nt = 0; nt < 4; ++nt) acc2[s][nt] = z;
    {
        half8 a[2][2];
        #pragma unroll
        for (int s = 0; s < 2; ++s)
            #pragma unroll
            for (int kg = 0; kg < 2; ++kg) {
                int rr = l & 15;
                int c0 = (kg * 32 + ((l >> 4) << 3)) ^ ((rr & 7) << 3);
                a[s][kg] = *(const half8*)&lsh[w][s][rr][c0];
            }
        const _Float16* pk3 = pk + 4 * 4096;
        #pragma unroll
        for (int nt = 0; nt < 4; ++nt)
            #pragma unroll
            for (int kg = 0; kg < 2; ++kg) {
                half8 b = *(const half8*)(pk3 + ((nt * 2 + kg) * 64 + l) * 8);
                acc2[0][nt] = __builtin_amdgcn_mfma_f32_16x16x32_f16(a[0][kg], b, acc2[0][nt], 0, 0, 0);
                acc2[1][nt] = __builtin_amdgcn_mfma_f32_16x16x32_f16(a[1][kg], b, acc2[1][nt], 0, 0, 0);
            }
    }

    float a2n[4];
    #pragma unroll
    for (int nt = 0; nt < 4; ++nt) a2n[nt] = ab2[nt * 16 + col];
    #pragma unroll
    for (int s = 0; s < 2; ++s)
        #pragma unroll
        for (int r = 0; r < 4; ++r) {
            int m = m0 + s * 16 + ((l >> 4) << 2) + r;
            if (m >= N_NODES) continue;
            #pragma unroll
            for (int nt = 0; nt < 4; ++nt)
                out[(size_t)m * 64 + nt * 16 + col] = acc2[s][nt][r] + a2n[nt];
        }
}

extern "C" void kernel_launch(void* const* d_in, const int* in_sizes, int n_in,
                              void* d_out, int out_size, void* d_ws, size_t ws_size,
                              hipStream_t stream) {
    const float* x   = (const float*)d_in[0];
    const int*   ei  = (const int*)d_in[1];
    const int*   ej  = ((const int*)d_in[1]) + N_EDGES;
    const float* pos = (const float*)d_in[2];
    const float* mw1 = (const float*)d_in[3];
    const float* mb1 = (const float*)d_in[4];
    const float* mw2 = (const float*)d_in[5];
    const float* mb2 = (const float*)d_in[6];
    const float* aw1 = (const float*)d_in[7];
    const float* ab1 = (const float*)d_in[8];
    const float* aw2 = (const float*)d_in[9];
    const float* ab2 = (const float*)d_in[10];

    char* ws = (char*)d_ws;
    int*       off    = (int*)(ws + WS_OFF);
    int*       pcur   = (int*)(ws + WS_PCUR);
    int*       B      = (int*)(ws + WS_B);
    int*       sj     = (int*)(ws + WS_SJ);
    float*     wcomb  = (float*)(ws + WS_WCOMB);
    float*     bcomb  = (float*)(ws + WS_BCOMB);
    _Float16*  pk     = (_Float16*)(ws + WS_PK);
    _Float16*  Q16    = (_Float16*)(ws + WS_Q);
    int*       binned = (int*)(ws + WS_BIN);
    _Float16*  hm16   = (_Float16*)(ws + WS_HM16);
    float*     out    = (float*)d_out;

    const int NBT = (N_NODES + 127) / 128;        // 782
    const int NBB = (N_EDGES + 2047) / 2048;      // 782
    hipLaunchKernelGGL(k_init0, dim3(1), dim3(128), 0, stream, pcur);
    hipLaunchKernelGGL(k_binc,  dim3(NBB), dim3(256), 0, stream, ei, ej, pcur, binned);
    hipLaunchKernelGGL(k_scanB, dim3(1), dim3(128), 0, stream, pcur, B);
    hipLaunchKernelGGL(k_fill3, dim3(NPART), dim3(256), 0, stream, binned, B, off, sj);
    hipLaunchKernelGGL(k_wcomb, dim3(17), dim3(256), 0, stream, mw2, mb2, aw1, wcomb, bcomb);
    hipLaunchKernelGGL(k_wpack, dim3(5), dim3(256), 0, stream, mw1, aw1, wcomb, aw2, pk);
    hipLaunchKernelGGL(k_pre,   dim3(NBT), dim3(256), 0, stream, x, pos, mw1, mb1, pk, out, Q16);
    hipLaunchKernelGGL(k_c1,    dim3((N_NODES + 3) / 4), dim3(256), 0, stream,
                       Q16, off, sj, out, hm16);
    hipLaunchKernelGGL(k_c2,    dim3(NBT), dim3(256), 0, stream,
                       x, hm16, pk, ab1, bcomb, ab2, off, out);
}